// Round 5
// baseline (615.329 us; speedup 1.0000x reference)
//
#include <hip/hip_runtime.h>
#include <hip/hip_bf16.h>
#include <math.h>

#define V_   32000
#define L_   4
#define H_   4
#define D_   256
#define DF_  1024
#define B_   2
#define T_   2048
#define DH_  64
#define NTOK (B_*T_)   // 4096

typedef __attribute__((ext_vector_type(8))) short bf16x8;
typedef __attribute__((ext_vector_type(4))) float f32x4;
typedef unsigned short u16;

#define GLOAD16(gsrc, ldst) \
  __builtin_amdgcn_global_load_lds((const __attribute__((address_space(1))) void*)(gsrc), \
                                   (__attribute__((address_space(3))) void*)(ldst), 16, 0, 0)

__device__ __forceinline__ u16 f2bf(float f) {
    unsigned int u = __builtin_bit_cast(unsigned int, f);
    u = (u + 0x7fff + ((u >> 16) & 1)) >> 16;   // RNE
    return (u16)u;
}

__device__ __forceinline__ int xcd_swizzle(int orig, int nwg) {
    return ((nwg & 7) == 0) ? ((orig & 7) * (nwg >> 3) + (orig >> 3)) : orig;
}

// ================= prep: all weight transposes f32[K,N] -> bf16[N,K] ================
__global__ __launch_bounds__(256) void prep_kernel(
    const float* __restrict__ Wq, const float* __restrict__ Wk,
    const float* __restrict__ Wv, const float* __restrict__ Wo,
    const float* __restrict__ W1, const float* __restrict__ W2,
    const float* __restrict__ hW,
    u16* __restrict__ WqkvT, u16* __restrict__ WoT,
    u16* __restrict__ W1T, u16* __restrict__ W2T, u16* __restrict__ hWT)
{
    int bidx = blockIdx.x;
    const float* src; u16* dst; int K, N, k0, n0;
    if (bidx < 1024) {                       // q,k,v,o  16 mats x 64 tiles
        int m = bidx >> 6, t = bidx & 63;
        int wt = m & 3, l = m >> 2;
        K = 256; N = 256;
        src = (wt == 0 ? Wq : wt == 1 ? Wk : wt == 2 ? Wv : Wo) + (size_t)l * 65536;
        dst = (wt < 3) ? WqkvT + (size_t)l * 196608 + (size_t)wt * 65536
                       : WoT + (size_t)l * 65536;
        k0 = (t >> 3) * 32; n0 = (t & 7) * 32;
    } else if (bidx < 2048) {                // W1: [256,1024] x 4
        int b = bidx - 1024; int l = b >> 8, t = b & 255;
        K = 256; N = 1024;
        src = W1 + (size_t)l * 262144; dst = W1T + (size_t)l * 262144;
        k0 = (t >> 5) * 32; n0 = (t & 31) * 32;
    } else if (bidx < 3072) {                // W2: [1024,256] x 4
        int b = bidx - 2048; int l = b >> 8, t = b & 255;
        K = 1024; N = 256;
        src = W2 + (size_t)l * 262144; dst = W2T + (size_t)l * 262144;
        k0 = (t >> 3) * 32; n0 = (t & 7) * 32;
    } else {                                 // head: [256,32000]
        int b = bidx - 3072;
        K = 256; N = 32000;
        src = hW; dst = hWT;
        k0 = (b / 1000) * 32; n0 = (b % 1000) * 32;
    }
    __shared__ float tile[32][33];
    int tc = threadIdx.x & 31, tr = threadIdx.x >> 5;
    #pragma unroll
    for (int i = 0; i < 4; i++)
        tile[tr + i*8][tc] = src[(size_t)(k0 + tr + i*8) * N + n0 + tc];
    __syncthreads();
    #pragma unroll
    for (int i = 0; i < 4; i++)
        dst[(size_t)(n0 + tr + i*8) * K + k0 + tc] = f2bf(tile[tc][tr + i*8]);
}

// ================= embed + LN1(l0) + QKV(l0) =================
// grid 128 x 512 threads; 32 rows per block
__global__ __launch_bounds__(512) void embed_qkv_kernel(
    const int* __restrict__ idx, const float* __restrict__ tok, const float* __restrict__ pos,
    const float* __restrict__ g, const float* __restrict__ bta,
    const u16* __restrict__ WqkvT0,
    const float* __restrict__ bq, const float* __restrict__ bk, const float* __restrict__ bv,
    float* __restrict__ x, u16* __restrict__ qkv)
{
    __shared__ u16 Bs[2][256*64];
    __shared__ u16 hS[32][264];

    int tid = threadIdx.x;
    int lane = tid & 63, w = tid >> 6;
    int lr = lane & 15, lg = lane >> 4;
    int wm = w >> 2, wn = w & 3;
    int bid = xcd_swizzle(blockIdx.x, 128);
    int row0 = bid * 32;

    // gather + LN: thread = (row 0..31, 16-col strip)
    {
        int grow = tid >> 4;
        int gcol = (tid & 15) * 16;
        int n = row0 + grow;
        int t = n & (T_ - 1);
        int id = idx[n];
        float vv[16];
        #pragma unroll
        for (int i = 0; i < 4; i++) {
            float4 a = *(const float4*)(tok + (size_t)id * D_ + gcol + i * 4);
            float4 b = *(const float4*)(pos + (size_t)t * D_ + gcol + i * 4);
            vv[i*4+0] = a.x + b.x; vv[i*4+1] = a.y + b.y;
            vv[i*4+2] = a.z + b.z; vv[i*4+3] = a.w + b.w;
        }
        float s = 0.f, q = 0.f;
        #pragma unroll
        for (int i = 0; i < 16; i++) { s += vv[i]; q += vv[i]*vv[i]; }
        #pragma unroll
        for (int o = 1; o <= 8; o <<= 1) { s += __shfl_xor(s, o); q += __shfl_xor(q, o); }
        float mu = s * (1.0f / D_);
        float var = q * (1.0f / D_) - mu * mu;
        float ri = rsqrtf(var + 1e-5f);
        #pragma unroll
        for (int i = 0; i < 16; i++) {
            x[(size_t)n * D_ + gcol + i] = vv[i];
            hS[grow][gcol + i] = f2bf((vv[i] - mu) * ri * g[gcol + i] + bta[gcol + i]);
        }
    }

    auto stageB = [&](int buf, const u16* BT, int K, int k0) {
        #pragma unroll
        for (int i = 0; i < 4; i++) {
            int o16 = tid + i * 512;
            int r = o16 >> 3;
            int sw = ((o16 & 7) << 4) ^ ((r & 7) << 4);
            GLOAD16(BT + (size_t)r * K + k0 + (sw >> 1), &Bs[buf][o16 * 8]);
        }
    };
    auto afH = [&](int t, int ks) -> bf16x8 {
        int rr = wm * 16 + lr;
        return *(const bf16x8*)(&hS[rr][(t * 128 + ks * 64 + lg * 16) >> 1]);
    };
    auto bfr = [&](int buf, int ni, int ks) -> bf16x8 {
        int rr = wn * 64 + ni * 16 + lr;
        return *(const bf16x8*)(&Bs[buf][rr * 64 + (((ks * 64 + lg * 16) ^ ((rr & 7) << 4)) >> 1)]);
    };

    stageB(0, WqkvT0, 256, 0);
    f32x4 acc[4] = {};
    for (int u = 0; u < 12; u++) {
        __syncthreads();
        if (u + 1 < 12)
            stageB((u + 1) & 1, WqkvT0 + (size_t)((u + 1) >> 2) * 65536, 256, ((u + 1) & 3) * 64);
        int t = u & 3;
        #pragma unroll
        for (int ks = 0; ks < 2; ks++) {
            bf16x8 a = afH(t, ks);
            __builtin_amdgcn_s_setprio(1);
            #pragma unroll
            for (int ni = 0; ni < 4; ni++)
                acc[ni] = __builtin_amdgcn_mfma_f32_16x16x32_bf16(a, bfr(u & 1, ni, ks), acc[ni], 0, 0, 0);
            __builtin_amdgcn_s_setprio(0);
        }
        if ((u & 3) == 3) {
            int sel = u >> 2;
            const float* bp = sel == 0 ? bq : sel == 1 ? bk : bv;
            #pragma unroll
            for (int ni = 0; ni < 4; ni++) {
                #pragma unroll
                for (int j = 0; j < 4; j++) {
                    int row = row0 + wm * 16 + lg * 4 + j;
                    int cc = wn * 64 + ni * 16 + lr;
                    float v = acc[ni][j] + bp[cc];
                    int bb = row >> 11, tt = row & (T_ - 1);
                    int hh = cc >> 6, dh = cc & 63;
                    qkv[(size_t)sel * NTOK * D_ +
                        ((((size_t)bb * H_ + hh) * T_) + tt) * DH_ + dh] = f2bf(v);
                }
                acc[ni] = (f32x4){0.f, 0.f, 0.f, 0.f};
            }
        }
    }
}

// ================= FFN megakernel: Wo+res+LN2 + FF1+GELU + FF2+res+LN(next) [+QKV(next)] ===========
// grid 128 x 512 threads; 32 rows per block
template<bool LAST>
__global__ __launch_bounds__(512) void ffn_kernel(
    const u16* __restrict__ ybuf,
    const u16* __restrict__ WoT, const float* __restrict__ bo,
    const u16* __restrict__ W1T, const float* __restrict__ b1,
    const u16* __restrict__ W2T, const float* __restrict__ b2,
    const float* __restrict__ ln2g, const float* __restrict__ ln2b,
    const float* __restrict__ lng, const float* __restrict__ lnb,   // next LN (ln1[l+1] or lnf)
    const u16* __restrict__ WqkvT,
    const float* __restrict__ bq, const float* __restrict__ bk, const float* __restrict__ bv,
    float* __restrict__ x, u16* __restrict__ hout, u16* __restrict__ qkv)
{
    __shared__ u16 Bs[2][256*64];     // 64 KB
    __shared__ u16 As[2][32*64];      // 8 KB
    __shared__ u16 hS[32][264];       // 16.5 KB
    __shared__ u16 ffS[32][520];      // 32.5 KB
    __shared__ float sred[4][32], qred[4][32];

    int tid = threadIdx.x;
    int lane = tid & 63, w = tid >> 6;
    int lr = lane & 15, lg = lane >> 4;
    int wm = w >> 2, wn = w & 3;
    int bid = xcd_swizzle(blockIdx.x, 128);
    int row0 = bid * 32;

    auto stageB = [&](int buf, const u16* BT, int K, int k0) {
        #pragma unroll
        for (int i = 0; i < 4; i++) {
            int o16 = tid + i * 512;
            int r = o16 >> 3;
            int sw = ((o16 & 7) << 4) ^ ((r & 7) << 4);
            GLOAD16(BT + (size_t)r * K + k0 + (sw >> 1), &Bs[buf][o16 * 8]);
        }
    };
    auto stageA = [&](int buf, int k0) {
        if (tid < 256) {
            int o16 = tid;
            int r = o16 >> 3;
            int sw = ((o16 & 7) << 4) ^ ((r & 7) << 4);
            GLOAD16(ybuf + (size_t)(row0 + r) * 256 + k0 + (sw >> 1), &As[buf][o16 * 8]);
        }
    };
    // tile schedule: 0-3 Wo | 4-11 FF1(c0,c1) | 12-19 FF2 k<512 | 20-27 FF1(c2,c3) | 28-35 FF2 k>=512 | 36-47 QKV
    auto prefetch = [&](int u) {
        int buf = u & 1;
        if (u < 4)       { stageA(buf, u * 64); stageB(buf, WoT, 256, u * 64); }
        else if (u < 12) { int v = u - 4;  stageB(buf, W1T + (size_t)(v >> 2) * 65536, 256, (v & 3) * 64); }
        else if (u < 20) { int v = u - 12; stageB(buf, W2T, 1024, v * 64); }
        else if (u < 28) { int v = u - 20; stageB(buf, W1T + (size_t)(2 + (v >> 2)) * 65536, 256, (v & 3) * 64); }
        else if (u < 36) { int v = u - 28; stageB(buf, W2T, 1024, 512 + v * 64); }
        else if (!LAST && u < 48) { int v = u - 36; stageB(buf, WqkvT + (size_t)(v >> 2) * 65536, 256, (v & 3) * 64); }
    };
    auto afA = [&](int buf, int ks) -> bf16x8 {
        int rr = wm * 16 + lr;
        return *(const bf16x8*)(&As[buf][rr * 64 + (((ks * 64 + lg * 16) ^ ((rr & 7) << 4)) >> 1)]);
    };
    auto afH = [&](int t, int ks) -> bf16x8 {
        int rr = wm * 16 + lr;
        return *(const bf16x8*)(&hS[rr][(t * 128 + ks * 64 + lg * 16) >> 1]);
    };
    auto afF = [&](int t, int ks) -> bf16x8 {
        int rr = wm * 16 + lr;
        return *(const bf16x8*)(&ffS[rr][(t * 128 + ks * 64 + lg * 16) >> 1]);
    };
    auto bfr = [&](int buf, int ni, int ks) -> bf16x8 {
        int rr = wn * 64 + ni * 16 + lr;
        return *(const bf16x8*)(&Bs[buf][rr * 64 + (((ks * 64 + lg * 16) ^ ((rr & 7) << 4)) >> 1)]);
    };

    float vals1[4][4];

    prefetch(0);

    // ---- S1: Wo GEMM (tiles 0..3)
    f32x4 acc1[4] = {};
    for (int u = 0; u < 4; u++) {
        __syncthreads();
        prefetch(u + 1);
        #pragma unroll
        for (int ks = 0; ks < 2; ks++) {
            bf16x8 a = afA(u & 1, ks);
            __builtin_amdgcn_s_setprio(1);
            #pragma unroll
            for (int ni = 0; ni < 4; ni++)
                acc1[ni] = __builtin_amdgcn_mfma_f32_16x16x32_bf16(a, bfr(u & 1, ni, ks), acc1[ni], 0, 0, 0);
            __builtin_amdgcn_s_setprio(0);
        }
    }
    // S1 epilogue: +bo +x residual -> x', LN2 -> hS
    {
        float rs[4] = {0,0,0,0}, rq[4] = {0,0,0,0};
        #pragma unroll
        for (int ni = 0; ni < 4; ni++)
            #pragma unroll
            for (int j = 0; j < 4; j++) {
                int row = row0 + wm * 16 + lg * 4 + j;
                int col = wn * 64 + ni * 16 + lr;
                float v = acc1[ni][j] + bo[col] + x[(size_t)row * D_ + col];
                x[(size_t)row * D_ + col] = v;
                vals1[ni][j] = v;
                rs[j] += v; rq[j] += v * v;
            }
        #pragma unroll
        for (int j = 0; j < 4; j++)
            #pragma unroll
            for (int o = 1; o <= 8; o <<= 1) { rs[j] += __shfl_xor(rs[j], o); rq[j] += __shfl_xor(rq[j], o); }
        if (lr == 0)
            #pragma unroll
            for (int j = 0; j < 4; j++) { sred[wn][wm*16 + lg*4 + j] = rs[j]; qred[wn][wm*16 + lg*4 + j] = rq[j]; }
        __syncthreads();
        #pragma unroll
        for (int j = 0; j < 4; j++) {
            int r = wm * 16 + lg * 4 + j;
            float mu = (sred[0][r] + sred[1][r] + sred[2][r] + sred[3][r]) * (1.0f / D_);
            float var = (qred[0][r] + qred[1][r] + qred[2][r] + qred[3][r]) * (1.0f / D_) - mu * mu;
            float ri = rsqrtf(var + 1e-5f);
            #pragma unroll
            for (int ni = 0; ni < 4; ni++) {
                int col = wn * 64 + ni * 16 + lr;
                hS[r][col] = f2bf((vals1[ni][j] - mu) * ri * ln2g[col] + ln2b[col]);
            }
        }
    }

    // ---- S2a: FF1 chunks 0,1 (tiles 4..11)   S3p0: FF2 k<512 (12..19)
    // ---- S2b: FF1 chunks 2,3 (20..27)        S3p1: FF2 k>=512 (28..35)
    f32x4 acc3[4] = {};
    f32x4 acc2[4] = {};
    for (int u = 4; u < 36; u++) {
        __syncthreads();
        prefetch(u + 1);
        bool isFF1 = (u < 12) || (u >= 20 && u < 28);
        if (isFF1) {
            int v = (u < 12) ? u - 4 : u - 20 + 8;    // 0..15 over 4 chunks
            int t = v & 3;
            #pragma unroll
            for (int ks = 0; ks < 2; ks++) {
                bf16x8 a = afH(t, ks);
                __builtin_amdgcn_s_setprio(1);
                #pragma unroll
                for (int ni = 0; ni < 4; ni++)
                    acc2[ni] = __builtin_amdgcn_mfma_f32_16x16x32_bf16(a, bfr(u & 1, ni, ks), acc2[ni], 0, 0, 0);
                __builtin_amdgcn_s_setprio(0);
            }
            if (t == 3) {
                int c = v >> 2;     // global chunk 0..3
                #pragma unroll
                for (int ni = 0; ni < 4; ni++) {
                    #pragma unroll
                    for (int j = 0; j < 4; j++) {
                        int rloc = wm * 16 + lg * 4 + j;
                        int col = wn * 64 + ni * 16 + lr;
                        float vv = acc2[ni][j] + b1[c * 256 + col];
                        vv = 0.5f * vv * (1.0f + erff(vv * 0.70710678118f));
                        ffS[rloc][(c & 1) * 256 + col] = f2bf(vv);
                    }
                    acc2[ni] = (f32x4){0.f, 0.f, 0.f, 0.f};
                }
            }
        } else {
            int t = (u < 20) ? u - 12 : u - 28;       // 0..7 within ff half
            #pragma unroll
            for (int ks = 0; ks < 2; ks++) {
                bf16x8 a = afF(t, ks);
                __builtin_amdgcn_s_setprio(1);
                #pragma unroll
                for (int ni = 0; ni < 4; ni++)
                    acc3[ni] = __builtin_amdgcn_mfma_f32_16x16x32_bf16(a, bfr(u & 1, ni, ks), acc3[ni], 0, 0, 0);
                __builtin_amdgcn_s_setprio(0);
            }
        }
    }
    // S3 epilogue: +b2 +x' residual -> x'', LN(next) -> hS (and hout if LAST)
    {
        float rs[4] = {0,0,0,0}, rq[4] = {0,0,0,0};
        #pragma unroll
        for (int ni = 0; ni < 4; ni++)
            #pragma unroll
            for (int j = 0; j < 4; j++) {
                int row = row0 + wm * 16 + lg * 4 + j;
                int col = wn * 64 + ni * 16 + lr;
                float v = acc3[ni][j] + b2[col] + vals1[ni][j];
                x[(size_t)row * D_ + col] = v;
                vals1[ni][j] = v;
                rs[j] += v; rq[j] += v * v;
            }
        #pragma unroll
        for (int j = 0; j < 4; j++)
            #pragma unroll
            for (int o = 1; o <= 8; o <<= 1) { rs[j] += __shfl_xor(rs[j], o); rq[j] += __shfl_xor(rq[j], o); }
        __syncthreads();    // hS readers (FF1) are done; also orders sred reuse
        if (lr == 0)
            #pragma unroll
            for (int j = 0; j < 4; j++) { sred[wn][wm*16 + lg*4 + j] = rs[j]; qred[wn][wm*16 + lg*4 + j] = rq[j]; }
        __syncthreads();
        #pragma unroll
        for (int j = 0; j < 4; j++) {
            int r = wm * 16 + lg * 4 + j;
            float mu = (sred[0][r] + sred[1][r] + sred[2][r] + sred[3][r]) * (1.0f / D_);
            float var = (qred[0][r] + qred[1][r] + qred[2][r] + qred[3][r]) * (1.0f / D_) - mu * mu;
            float ri = rsqrtf(var + 1e-5f);
            #pragma unroll
            for (int ni = 0; ni < 4; ni++) {
                int col = wn * 64 + ni * 16 + lr;
                float hv = (vals1[ni][j] - mu) * ri * lng[col] + lnb[col];
                hS[r][col] = f2bf(hv);
                if (LAST) {
                    int row = row0 + r;
                    hout[(size_t)row * D_ + col] = f2bf(hv);
                }
            }
        }
    }

    // ---- QKV for next layer (tiles 36..47)
    if constexpr (!LAST) {
        f32x4 acc4[4] = {};
        for (int u = 36; u < 48; u++) {
            __syncthreads();
            prefetch(u + 1);
            int t = (u - 36) & 3;
            #pragma unroll
            for (int ks = 0; ks < 2; ks++) {
                bf16x8 a = afH(t, ks);
                __builtin_amdgcn_s_setprio(1);
                #pragma unroll
                for (int ni = 0; ni < 4; ni++)
                    acc4[ni] = __builtin_amdgcn_mfma_f32_16x16x32_bf16(a, bfr(u & 1, ni, ks), acc4[ni], 0, 0, 0);
                __builtin_amdgcn_s_setprio(0);
            }
            if (t == 3) {
                int sel = (u - 36) >> 2;
                const float* bp = sel == 0 ? bq : sel == 1 ? bk : bv;
                #pragma unroll
                for (int ni = 0; ni < 4; ni++) {
                    #pragma unroll
                    for (int j = 0; j < 4; j++) {
                        int row = row0 + wm * 16 + lg * 4 + j;
                        int cc = wn * 64 + ni * 16 + lr;
                        float v = acc4[ni][j] + bp[cc];
                        int bb = row >> 11, tt = row & (T_ - 1);
                        int hh = cc >> 6, dh = cc & 63;
                        qkv[(size_t)sel * NTOK * D_ +
                            ((((size_t)bb * H_ + hh) * T_) + tt) * DH_ + dh] = f2bf(v);
                    }
                    acc4[ni] = (f32x4){0.f, 0.f, 0.f, 0.f};
                }
            }
        }
    }
}

// ================= MFMA causal flash attention (unchanged) =================
__global__ __launch_bounds__(256) void attn_kernel(
    const u16* __restrict__ q, const u16* __restrict__ k,
    const u16* __restrict__ v, u16* __restrict__ y)
{
    int qb = blockIdx.x;
    int bh = blockIdx.y;
    int bidx = bh >> 2, h = bh & 3;
    const u16* qp = q + (size_t)bh * T_ * DH_;
    const u16* kp = k + (size_t)bh * T_ * DH_;
    const u16* vp = v + (size_t)bh * T_ * DH_;

    __shared__ u16 Qs[64*64];
    __shared__ u16 Ks[2][64*64];
    __shared__ u16 VT[2][64*72];
    __shared__ u16 Ps[4][16*72];

    int tid = threadIdx.x;
    int lane = tid & 63, w = tid >> 6;
    int lr = lane & 15, lg = lane >> 4;
    int vkey = tid & 63;
    int vdh0 = (tid >> 6) * 8;

    #pragma unroll
    for (int i = 0; i < 2; i++) {
        int o16 = tid + i * 256;
        int r = o16 >> 3;
        int sw = ((o16 & 7) << 4) ^ ((r & 7) << 4);
        GLOAD16(qp + (size_t)(qb * 64 + r) * DH_ + (sw >> 1), &Qs[o16 * 8]);
        GLOAD16(kp + (size_t)r * DH_ + (sw >> 1), &Ks[0][o16 * 8]);
    }
    bf16x8 vva = *(const bf16x8*)(vp + (size_t)vkey * DH_ + vdh0);
    bf16x8 vvb = *(const bf16x8*)(vp + (size_t)vkey * DH_ + vdh0 + 32);
    __syncthreads();
    #pragma unroll
    for (int e = 0; e < 8; e++) {
        VT[0][(vdh0 + e) * 72 + vkey] = (u16)vva[e];
        VT[0][(vdh0 + 32 + e) * 72 + vkey] = (u16)vvb[e];
    }
    bf16x8 qa[2];
    #pragma unroll
    for (int ks = 0; ks < 2; ks++) {
        int rr = w * 16 + lr;
        qa[ks] = *(const bf16x8*)(Qs + rr * 64 + (((ks * 64 + lg * 16) ^ ((rr & 7) << 4)) >> 1));
    }
    __syncthreads();

    float m[4], lden[4];
    f32x4 o[4] = {};
    #pragma unroll
    for (int j = 0; j < 4; j++) { m[j] = -1e30f; lden[j] = 0.0f; }

    for (int kc = 0; kc <= qb; kc++) {
        int cur = kc & 1, nxt = cur ^ 1;
        bf16x8 nva, nvb;
        if (kc < qb) {
            #pragma unroll
            for (int i = 0; i < 2; i++) {
                int o16 = tid + i * 256;
                int r = o16 >> 3;
                int sw = ((o16 & 7) << 4) ^ ((r & 7) << 4);
                GLOAD16(kp + (size_t)((kc + 1) * 64 + r) * DH_ + (sw >> 1), &Ks[nxt][o16 * 8]);
            }
            nva = *(const bf16x8*)(vp + (size_t)((kc + 1) * 64 + vkey) * DH_ + vdh0);
            nvb = *(const bf16x8*)(vp + (size_t)((kc + 1) * 64 + vkey) * DH_ + vdh0 + 32);
        }

        f32x4 sc[4];
        #pragma unroll
        for (int ct = 0; ct < 4; ct++) {
            f32x4 s = {};
            __builtin_amdgcn_s_setprio(1);
            #pragma unroll
            for (int ks = 0; ks < 2; ks++) {
                int rr = ct * 16 + lr;
                bf16x8 kb = *(const bf16x8*)(&Ks[cur][rr * 64 + (((ks * 64 + lg * 16) ^ ((rr & 7) << 4)) >> 1)]);
                s = __builtin_amdgcn_mfma_f32_16x16x32_bf16(qa[ks], kb, s, 0, 0, 0);
            }
            __builtin_amdgcn_s_setprio(0);
            sc[ct] = s;
        }
        float mloc[4];
        #pragma unroll
        for (int j = 0; j < 4; j++) mloc[j] = -1e30f;
        #pragma unroll
        for (int ct = 0; ct < 4; ct++)
            #pragma unroll
            for (int j = 0; j < 4; j++) {
                float s = sc[ct][j] * 0.125f;
                if (kc == qb && (ct * 16 + lr) > (w * 16 + lg * 4 + j)) s = -1e30f;
                sc[ct][j] = s;
                mloc[j] = fmaxf(mloc[j], s);
            }
        #pragma unroll
        for (int j = 0; j < 4; j++) {
            mloc[j] = fmaxf(mloc[j], __shfl_xor(mloc[j], 1));
            mloc[j] = fmaxf(mloc[j], __shfl_xor(mloc[j], 2));
            mloc[j] = fmaxf(mloc[j], __shfl_xor(mloc[j], 4));
            mloc[j] = fmaxf(mloc[j], __shfl_xor(mloc[j], 8));
        }
        float f[4], rs[4];
        #pragma unroll
        for (int j = 0; j < 4; j++) {
            float nm = fmaxf(m[j], mloc[j]);
            f[j] = __expf(m[j] - nm);
            m[j] = nm;
            rs[j] = 0.0f;
        }
        #pragma unroll
        for (int ct = 0; ct < 4; ct++)
            #pragma unroll
            for (int j = 0; j < 4; j++) {
                float p = __expf(sc[ct][j] - m[j]);
                rs[j] += p;
                Ps[w][(lg * 4 + j) * 72 + ct * 16 + lr] = f2bf(p);
            }
        #pragma unroll
        for (int j = 0; j < 4; j++) {
            rs[j] += __shfl_xor(rs[j], 1);
            rs[j] += __shfl_xor(rs[j], 2);
            rs[j] += __shfl_xor(rs[j], 4);
            rs[j] += __shfl_xor(rs[j], 8);
            lden[j] = lden[j] * f[j] + rs[j];
        }
        #pragma unroll
        for (int dt = 0; dt < 4; dt++)
            #pragma unroll
            for (int j = 0; j < 4; j++)
                o[dt][j] *= f[j];
        #pragma unroll
        for (int ks = 0; ks < 2; ks++) {
            bf16x8 pa = *(const bf16x8*)(&Ps[w][lr * 72 + ks * 32 + lg * 8]);
            __builtin_amdgcn_s_setprio(1);
            #pragma unroll
            for (int dt = 0; dt < 4; dt++) {
                bf16x8 vb = *(const bf16x8*)(&VT[cur][(dt * 16 + lr) * 72 + ks * 32 + lg * 8]);
                o[dt] = __builtin_amdgcn_mfma_f32_16x16x32_bf16(pa, vb, o[dt], 0, 0, 0);
            }
            __builtin_amdgcn_s_setprio(0);
        }
        if (kc < qb) {
            #pragma unroll
            for (int e = 0; e < 8; e++) {
                VT[nxt][(vdh0 + e) * 72 + vkey] = (u16)nva[e];
                VT[nxt][(vdh0 + 32 + e) * 72 + vkey] = (u16)nvb[e];
            }
        }
        __syncthreads();
    }

    #pragma unroll
    for (int j = 0; j < 4; j++) {
        float inv = 1.0f / lden[j];
        int q_g = qb * 64 + w * 16 + lg * 4 + j;
        size_t base = ((size_t)(bidx * T_ + q_g)) * D_ + h * DH_;
        #pragma unroll
        for (int dt = 0; dt < 4; dt++)
            y[base + dt * 16 + lr] = f2bf(o[dt][j] * inv);
    }
}

// ================= head GEMM (128x128 MFMA, double-buffered) =================
__global__ __launch_bounds__(256) void head_gemm(
    const u16* __restrict__ A, const u16* __restrict__ BT,
    const float* __restrict__ bias, float* __restrict__ C,
    int M, int N, int K)
{
    __shared__ u16 As[2][128*64];
    __shared__ u16 Bs[2][128*64];
    int tid = threadIdx.x;
    int lane = tid & 63, w = tid >> 6;
    int lr = lane & 15, lg = lane >> 4;
    int wm = w >> 1, wn = w & 1;

    int gx = gridDim.x;
    int nwg = gx * gridDim.y;
    int orig = blockIdx.y * gx + blockIdx.x;
    int bid = xcd_swizzle(orig, nwg);
    int row0 = (bid / gx) * 128, col0 = (bid % gx) * 128;

    f32x4 acc[4][4] = {};

    auto stage = [&](int buf, int k0) {
        #pragma unroll
        for (int i = 0; i < 4; i++) {
            int o16 = tid + i * 256;
            int r = o16 >> 3;
            int sw = ((o16 & 7) << 4) ^ ((r & 7) << 4);
            GLOAD16(A + (size_t)(row0 + r) * K + k0 + (sw >> 1), &As[buf][o16 * 8]);
            GLOAD16(BT + (size_t)(col0 + r) * K + k0 + (sw >> 1), &Bs[buf][o16 * 8]);
        }
    };

    stage(0, 0);
    int nk = K >> 6;
    for (int t = 0; t < nk; t++) {
        int cur = t & 1;
        __syncthreads();
        if (t + 1 < nk) stage(cur ^ 1, (t + 1) << 6);
        #pragma unroll
        for (int ks = 0; ks < 2; ks++) {
            bf16x8 af[4], bfr[4];
            #pragma unroll
            for (int mi = 0; mi < 4; mi++) {
                int rr = wm * 64 + mi * 16 + lr;
                af[mi] = *(const bf16x8*)(&As[cur][rr * 64 + (((ks * 64 + lg * 16) ^ ((rr & 7) << 4)) >> 1)]);
            }
            #pragma unroll
            for (int ni = 0; ni < 4; ni++) {
                int rr = wn * 64 + ni * 16 + lr;
                bfr[ni] = *(const bf16x8*)(&Bs[cur][rr * 64 + (((ks * 64 + lg * 16) ^ ((rr & 7) << 4)) >> 1)]);
            }
            __builtin_amdgcn_s_setprio(1);
            #pragma unroll
            for (int mi = 0; mi < 4; mi++)
                #pragma unroll
                for (int ni = 0; ni < 4; ni++)
                    acc[mi][ni] = __builtin_amdgcn_mfma_f32_16x16x32_bf16(af[mi], bfr[ni], acc[mi][ni], 0, 0, 0);
            __builtin_amdgcn_s_setprio(0);
        }
    }

    #pragma unroll
    for (int mi = 0; mi < 4; mi++)
        #pragma unroll
        for (int ni = 0; ni < 4; ni++)
            #pragma unroll
            for (int j = 0; j < 4; j++) {
                int row = row0 + wm * 64 + mi * 16 + lg * 4 + j;
                int col = col0 + wn * 64 + ni * 16 + lr;
                C[(size_t)row * N + col] = acc[mi][ni][j] + bias[col];
            }
}

// ================= host launch =================
extern "C" void kernel_launch(void* const* d_in, const int* in_sizes, int n_in,
                              void* d_out, int out_size, void* d_ws, size_t ws_size,
                              hipStream_t stream)
{
    const int*   idx  = (const int*)d_in[0];
    const float* tok  = (const float*)d_in[1];
    const float* pos  = (const float*)d_in[2];
    const float* Wq   = (const float*)d_in[3];
    const float* bq   = (const float*)d_in[4];
    const float* Wk   = (const float*)d_in[5];
    const float* bk   = (const float*)d_in[6];
    const float* Wv   = (const float*)d_in[7];
    const float* bv   = (const float*)d_in[8];
    const float* Wo   = (const float*)d_in[9];
    const float* bo   = (const float*)d_in[10];
    const float* ln1g = (const float*)d_in[11];
    const float* ln1b = (const float*)d_in[12];
    const float* W1   = (const float*)d_in[13];
    const float* b1   = (const float*)d_in[14];
    const float* W2   = (const float*)d_in[15];
    const float* b2   = (const float*)d_in[16];
    const float* ln2g = (const float*)d_in[17];
    const float* ln2b = (const float*)d_in[18];
    const float* lnfg = (const float*)d_in[19];
    const float* lnfb = (const float*)d_in[20];
    const float* hW   = (const float*)d_in[21];
    const float* hb   = (const float*)d_in[22];

    char* p = (char*)d_ws;
    float* x     = (float*)p;           p += (size_t)NTOK * D_ * 4;
    u16* hbuf    = (u16*)p;             p += (size_t)NTOK * D_ * 2;
    u16* qkvbuf  = (u16*)p;             p += (size_t)3 * NTOK * D_ * 2;
    u16* ybuf    = (u16*)p;             p += (size_t)NTOK * D_ * 2;
    u16* WqkvT   = (u16*)p;             p += (size_t)L_ * 768 * D_ * 2;
    u16* WoT     = (u16*)p;             p += (size_t)L_ * D_ * D_ * 2;
    u16* W1T     = (u16*)p;             p += (size_t)L_ * D_ * DF_ * 2;
    u16* W2T     = (u16*)p;             p += (size_t)L_ * DF_ * D_ * 2;
    u16* hWT     = (u16*)p;             p += (size_t)V_ * D_ * 2;

    u16* qbuf = qkvbuf;
    u16* kbuf = qkvbuf + (size_t)NTOK * D_;
    u16* vbuf = qkvbuf + (size_t)2 * NTOK * D_;

    prep_kernel<<<11072, 256, 0, stream>>>(Wq, Wk, Wv, Wo, W1, W2, hW,
                                           WqkvT, WoT, W1T, W2T, hWT);

    embed_qkv_kernel<<<128, 512, 0, stream>>>(idx, tok, pos, ln1g, ln1b,
                                              WqkvT, bq, bk, bv, x, qkvbuf);

    dim3 gAttn(T_ / 64, B_ * H_);        // (32, 8)
    for (int l = 0; l < L_; l++) {
        attn_kernel<<<gAttn, 256, 0, stream>>>(qbuf, kbuf, vbuf, ybuf);
        if (l < L_ - 1) {
            ffn_kernel<false><<<128, 512, 0, stream>>>(
                ybuf, WoT + (size_t)l * 65536, bo + l * D_,
                W1T + (size_t)l * 262144, b1 + l * DF_,
                W2T + (size_t)l * 262144, b2 + l * D_,
                ln2g + l * D_, ln2b + l * D_,
                ln1g + (l + 1) * D_, ln1b + (l + 1) * D_,
                WqkvT + (size_t)(l + 1) * 196608,
                bq + (l + 1) * D_, bk + (l + 1) * D_, bv + (l + 1) * D_,
                x, nullptr, qkvbuf);
        } else {
            ffn_kernel<true><<<128, 512, 0, stream>>>(
                ybuf, WoT + (size_t)l * 65536, bo + l * D_,
                W1T + (size_t)l * 262144, b1 + l * DF_,
                W2T + (size_t)l * 262144, b2 + l * D_,
                ln2g + l * D_, ln2b + l * D_,
                lnfg, lnfb,
                nullptr, nullptr, nullptr, nullptr,
                x, hbuf, nullptr);
        }
    }

    dim3 gHead(V_ / 128, NTOK / 128);    // (250, 32)
    head_gemm<<<gHead, 256, 0, stream>>>(hbuf, hWT, hb, (float*)d_out, NTOK, V_, D_);
}

// Round 6
// 593.508 us; speedup vs baseline: 1.0368x; 1.0368x over previous
//
#include <hip/hip_runtime.h>
#include <hip/hip_bf16.h>
#include <math.h>

#define V_   32000
#define L_   4
#define H_   4
#define D_   256
#define DF_  1024
#define B_   2
#define T_   2048
#define DH_  64
#define NTOK (B_*T_)   // 4096

typedef __attribute__((ext_vector_type(8))) short bf16x8;
typedef __attribute__((ext_vector_type(4))) float f32x4;
typedef unsigned short u16;

#define GLOAD16(gsrc, ldst) \
  __builtin_amdgcn_global_load_lds((const __attribute__((address_space(1))) void*)(gsrc), \
                                   (__attribute__((address_space(3))) void*)(ldst), 16, 0, 0)

__device__ __forceinline__ u16 f2bf(float f) {
    unsigned int u = __builtin_bit_cast(unsigned int, f);
    u = (u + 0x7fff + ((u >> 16) & 1)) >> 16;   // RNE
    return (u16)u;
}

__device__ __forceinline__ int xcd_swizzle(int orig, int nwg) {
    return ((nwg & 7) == 0) ? ((orig & 7) * (nwg >> 3) + (orig >> 3)) : orig;
}

// ================= prep: all weight transposes f32[K,N] -> bf16[N,K] ================
__global__ __launch_bounds__(256) void prep_kernel(
    const float* __restrict__ Wq, const float* __restrict__ Wk,
    const float* __restrict__ Wv, const float* __restrict__ Wo,
    const float* __restrict__ W1, const float* __restrict__ W2,
    const float* __restrict__ hW,
    u16* __restrict__ WqkvT, u16* __restrict__ WoT,
    u16* __restrict__ W1T, u16* __restrict__ W2T, u16* __restrict__ hWT)
{
    int bidx = blockIdx.x;
    const float* src; u16* dst; int K, N, k0, n0;
    if (bidx < 1024) {
        int m = bidx >> 6, t = bidx & 63;
        int wt = m & 3, l = m >> 2;
        K = 256; N = 256;
        src = (wt == 0 ? Wq : wt == 1 ? Wk : wt == 2 ? Wv : Wo) + (size_t)l * 65536;
        dst = (wt < 3) ? WqkvT + (size_t)l * 196608 + (size_t)wt * 65536
                       : WoT + (size_t)l * 65536;
        k0 = (t >> 3) * 32; n0 = (t & 7) * 32;
    } else if (bidx < 2048) {
        int b = bidx - 1024; int l = b >> 8, t = b & 255;
        K = 256; N = 1024;
        src = W1 + (size_t)l * 262144; dst = W1T + (size_t)l * 262144;
        k0 = (t >> 5) * 32; n0 = (t & 31) * 32;
    } else if (bidx < 3072) {
        int b = bidx - 2048; int l = b >> 8, t = b & 255;
        K = 1024; N = 256;
        src = W2 + (size_t)l * 262144; dst = W2T + (size_t)l * 262144;
        k0 = (t >> 3) * 32; n0 = (t & 7) * 32;
    } else {
        int b = bidx - 3072;
        K = 256; N = 32000;
        src = hW; dst = hWT;
        k0 = (b / 1000) * 32; n0 = (b % 1000) * 32;
    }
    __shared__ float tile[32][33];
    int tc = threadIdx.x & 31, tr = threadIdx.x >> 5;
    #pragma unroll
    for (int i = 0; i < 4; i++)
        tile[tr + i*8][tc] = src[(size_t)(k0 + tr + i*8) * N + n0 + tc];
    __syncthreads();
    #pragma unroll
    for (int i = 0; i < 4; i++)
        dst[(size_t)(n0 + tr + i*8) * K + k0 + tc] = f2bf(tile[tc][tr + i*8]);
}

// ================= embed + LN1(l0) + QKV(l0): 256 blocks x 256t, 16 rows/block =========
__global__ __launch_bounds__(256) void embed_qkv_kernel(
    const int* __restrict__ idx, const float* __restrict__ tok, const float* __restrict__ pos,
    const float* __restrict__ g, const float* __restrict__ bta,
    const u16* __restrict__ WqkvT0,
    const float* __restrict__ bq, const float* __restrict__ bk, const float* __restrict__ bv,
    float* __restrict__ x, u16* __restrict__ qkv)
{
    __shared__ u16 Bs[2][256*64];
    __shared__ u16 hS[16][264];

    int tid = threadIdx.x;
    int lane = tid & 63, w = tid >> 6;
    int lr = lane & 15, lg = lane >> 4;
    int bid = xcd_swizzle(blockIdx.x, 256);
    int row0 = bid * 16;

    // gather + LN: thread = (row = tid>>4, 16-col strip = tid&15)
    {
        int grow = tid >> 4;
        int gcol = (tid & 15) * 16;
        int n = row0 + grow;
        int t = n & (T_ - 1);
        int id = idx[n];
        float vv[16];
        #pragma unroll
        for (int i = 0; i < 4; i++) {
            float4 a = *(const float4*)(tok + (size_t)id * D_ + gcol + i * 4);
            float4 b = *(const float4*)(pos + (size_t)t * D_ + gcol + i * 4);
            vv[i*4+0] = a.x + b.x; vv[i*4+1] = a.y + b.y;
            vv[i*4+2] = a.z + b.z; vv[i*4+3] = a.w + b.w;
        }
        float s = 0.f, q = 0.f;
        #pragma unroll
        for (int i = 0; i < 16; i++) { s += vv[i]; q += vv[i]*vv[i]; }
        #pragma unroll
        for (int o = 1; o <= 8; o <<= 1) { s += __shfl_xor(s, o); q += __shfl_xor(q, o); }
        float mu = s * (1.0f / D_);
        float var = q * (1.0f / D_) - mu * mu;
        float ri = rsqrtf(var + 1e-5f);
        #pragma unroll
        for (int i = 0; i < 16; i++) {
            x[(size_t)n * D_ + gcol + i] = vv[i];
            hS[grow][gcol + i] = f2bf((vv[i] - mu) * ri * g[gcol + i] + bta[gcol + i]);
        }
    }

    auto stageQ = [&](int buf, int u) {
        const u16* BT = WqkvT0 + (size_t)(u >> 2) * 65536;
        int k0 = (u & 3) * 64;
        #pragma unroll
        for (int i = 0; i < 8; i++) {
            int o16 = tid + i * 256;
            int r = o16 >> 3;
            int sw = ((o16 & 7) << 4) ^ ((r & 7) << 4);
            GLOAD16(BT + (size_t)r * 256 + k0 + (sw >> 1), &Bs[buf][o16 * 8]);
        }
    };
    auto afH = [&](int t, int ks) -> bf16x8 {
        return *(const bf16x8*)(&hS[lr][(t * 128 + ks * 64 + lg * 16) >> 1]);
    };
    auto bfr = [&](int buf, int ni, int ks) -> bf16x8 {
        int rr = w * 64 + ni * 16 + lr;
        return *(const bf16x8*)(&Bs[buf][rr * 64 + (((ks * 64 + lg * 16) ^ ((rr & 7) << 4)) >> 1)]);
    };

    stageQ(0, 0);
    f32x4 acc[4] = {};
    for (int u = 0; u < 12; u++) {
        __syncthreads();
        if (u + 1 < 12) stageQ((u + 1) & 1, u + 1);
        int t = u & 3;
        #pragma unroll
        for (int ks = 0; ks < 2; ks++) {
            bf16x8 a = afH(t, ks);
            __builtin_amdgcn_s_setprio(1);
            #pragma unroll
            for (int ni = 0; ni < 4; ni++)
                acc[ni] = __builtin_amdgcn_mfma_f32_16x16x32_bf16(a, bfr(u & 1, ni, ks), acc[ni], 0, 0, 0);
            __builtin_amdgcn_s_setprio(0);
        }
        if (t == 3) {
            int sel = u >> 2;
            const float* bp = sel == 0 ? bq : sel == 1 ? bk : bv;
            #pragma unroll
            for (int ni = 0; ni < 4; ni++) {
                #pragma unroll
                for (int j = 0; j < 4; j++) {
                    int row = row0 + lg * 4 + j;
                    int cc = w * 64 + ni * 16 + lr;
                    float v = acc[ni][j] + bp[cc];
                    int bb = row >> 11, tt = row & (T_ - 1);
                    int hh = cc >> 6, dh = cc & 63;
                    qkv[(size_t)sel * NTOK * D_ +
                        ((((size_t)bb * H_ + hh) * T_) + tt) * DH_ + dh] = f2bf(v);
                }
                acc[ni] = (f32x4){0.f, 0.f, 0.f, 0.f};
            }
        }
    }
}

// ================= Wo + residual + LN2: 256 blocks x 256t, 16 rows/block ==========
__global__ __launch_bounds__(256) void wo_ln_kernel(
    const u16* __restrict__ ybuf, const u16* __restrict__ WoT, const float* __restrict__ bo,
    const float* __restrict__ ln2g, const float* __restrict__ ln2b,
    float* __restrict__ x, u16* __restrict__ hbuf)
{
    __shared__ u16 As[2][16*64];
    __shared__ u16 Bs[2][256*64];
    __shared__ float sred[4][16], qred[4][16];

    int tid = threadIdx.x;
    int lane = tid & 63, w = tid >> 6;
    int lr = lane & 15, lg = lane >> 4;
    int bid = xcd_swizzle(blockIdx.x, 256);
    int row0 = bid * 16;

    auto stage = [&](int buf, int k0) {
        #pragma unroll
        for (int i = 0; i < 8; i++) {
            int o16 = tid + i * 256;
            int r = o16 >> 3;
            int sw = ((o16 & 7) << 4) ^ ((r & 7) << 4);
            GLOAD16(WoT + (size_t)r * 256 + k0 + (sw >> 1), &Bs[buf][o16 * 8]);
        }
        if (tid < 128) {
            int r = tid >> 3;
            int sw = ((tid & 7) << 4) ^ ((r & 7) << 4);
            GLOAD16(ybuf + (size_t)(row0 + r) * 256 + k0 + (sw >> 1), &As[buf][tid * 8]);
        }
    };
    auto afA = [&](int buf, int ks) -> bf16x8 {
        return *(const bf16x8*)(&As[buf][lr * 64 + (((ks * 64 + lg * 16) ^ ((lr & 7) << 4)) >> 1)]);
    };
    auto bfr = [&](int buf, int ni, int ks) -> bf16x8 {
        int rr = w * 64 + ni * 16 + lr;
        return *(const bf16x8*)(&Bs[buf][rr * 64 + (((ks * 64 + lg * 16) ^ ((rr & 7) << 4)) >> 1)]);
    };

    stage(0, 0);
    f32x4 acc[4] = {};
    for (int t = 0; t < 4; t++) {
        __syncthreads();
        if (t + 1 < 4) stage((t + 1) & 1, (t + 1) * 64);
        #pragma unroll
        for (int ks = 0; ks < 2; ks++) {
            bf16x8 a = afA(t & 1, ks);
            __builtin_amdgcn_s_setprio(1);
            #pragma unroll
            for (int ni = 0; ni < 4; ni++)
                acc[ni] = __builtin_amdgcn_mfma_f32_16x16x32_bf16(a, bfr(t & 1, ni, ks), acc[ni], 0, 0, 0);
            __builtin_amdgcn_s_setprio(0);
        }
    }

    float vals[4][4];
    float rs[4] = {0,0,0,0}, rq[4] = {0,0,0,0};
    #pragma unroll
    for (int ni = 0; ni < 4; ni++)
        #pragma unroll
        for (int j = 0; j < 4; j++) {
            int row = row0 + lg * 4 + j;
            int col = w * 64 + ni * 16 + lr;
            float v = acc[ni][j] + bo[col] + x[(size_t)row * D_ + col];
            x[(size_t)row * D_ + col] = v;
            vals[ni][j] = v;
            rs[j] += v; rq[j] += v * v;
        }
    #pragma unroll
    for (int j = 0; j < 4; j++)
        #pragma unroll
        for (int o = 1; o <= 8; o <<= 1) { rs[j] += __shfl_xor(rs[j], o); rq[j] += __shfl_xor(rq[j], o); }
    if (lr == 0)
        #pragma unroll
        for (int j = 0; j < 4; j++) { sred[w][lg*4 + j] = rs[j]; qred[w][lg*4 + j] = rq[j]; }
    __syncthreads();
    #pragma unroll
    for (int j = 0; j < 4; j++) {
        int r = lg * 4 + j;
        float mu = (sred[0][r] + sred[1][r] + sred[2][r] + sred[3][r]) * (1.0f / D_);
        float var = (qred[0][r] + qred[1][r] + qred[2][r] + qred[3][r]) * (1.0f / D_) - mu * mu;
        float ri = rsqrtf(var + 1e-5f);
        int row = row0 + r;
        #pragma unroll
        for (int ni = 0; ni < 4; ni++) {
            int col = w * 64 + ni * 16 + lr;
            hbuf[(size_t)row * D_ + col] = f2bf((vals[ni][j] - mu) * ri * ln2g[col] + ln2b[col]);
        }
    }
}

// ================= FF1 + GELU: 64x64 tiles, 1024 blocks =================
__global__ __launch_bounds__(256) void ff1_kernel(
    const u16* __restrict__ A, const u16* __restrict__ BT,
    const float* __restrict__ bias, u16* __restrict__ C)
{
    __shared__ u16 As[2][64*64];
    __shared__ u16 Bs[2][64*64];
    int tid = threadIdx.x;
    int lane = tid & 63, w = tid >> 6;
    int lr = lane & 15, lg = lane >> 4;
    int wm = w >> 1, wn = w & 1;

    int gx = gridDim.x;
    int nwg = gx * gridDim.y;
    int orig = blockIdx.y * gx + blockIdx.x;
    int bid = xcd_swizzle(orig, nwg);
    int row0 = (bid / gx) * 64, col0 = (bid % gx) * 64;

    auto stage = [&](int buf, int k0) {
        #pragma unroll
        for (int i = 0; i < 2; i++) {
            int o16 = tid + i * 256;
            int r = o16 >> 3;
            int sw = ((o16 & 7) << 4) ^ ((r & 7) << 4);
            GLOAD16(A + (size_t)(row0 + r) * 256 + k0 + (sw >> 1), &As[buf][o16 * 8]);
            GLOAD16(BT + (size_t)(col0 + r) * 256 + k0 + (sw >> 1), &Bs[buf][o16 * 8]);
        }
    };

    stage(0, 0);
    f32x4 acc[2][2] = {};
    for (int t = 0; t < 4; t++) {
        __syncthreads();
        if (t + 1 < 4) stage((t + 1) & 1, (t + 1) * 64);
        #pragma unroll
        for (int ks = 0; ks < 2; ks++) {
            bf16x8 af[2], bfv[2];
            #pragma unroll
            for (int mi = 0; mi < 2; mi++) {
                int rr = wm * 32 + mi * 16 + lr;
                af[mi] = *(const bf16x8*)(&As[t & 1][rr * 64 + (((ks * 64 + lg * 16) ^ ((rr & 7) << 4)) >> 1)]);
            }
            #pragma unroll
            for (int ni = 0; ni < 2; ni++) {
                int rr = wn * 32 + ni * 16 + lr;
                bfv[ni] = *(const bf16x8*)(&Bs[t & 1][rr * 64 + (((ks * 64 + lg * 16) ^ ((rr & 7) << 4)) >> 1)]);
            }
            __builtin_amdgcn_s_setprio(1);
            #pragma unroll
            for (int mi = 0; mi < 2; mi++)
                #pragma unroll
                for (int ni = 0; ni < 2; ni++)
                    acc[mi][ni] = __builtin_amdgcn_mfma_f32_16x16x32_bf16(af[mi], bfv[ni], acc[mi][ni], 0, 0, 0);
            __builtin_amdgcn_s_setprio(0);
        }
    }

    #pragma unroll
    for (int mi = 0; mi < 2; mi++)
        #pragma unroll
        for (int ni = 0; ni < 2; ni++)
            #pragma unroll
            for (int j = 0; j < 4; j++) {
                int row = row0 + wm * 32 + mi * 16 + lg * 4 + j;
                int col = col0 + wn * 32 + ni * 16 + lr;
                float v = acc[mi][ni][j] + bias[col];
                v = 0.5f * v * (1.0f + erff(v * 0.70710678118f));
                C[(size_t)row * DF_ + col] = f2bf(v);
            }
}

// ================= FF2 + residual + LN(next) + QKV(next): 256 blocks, 16 rows =========
template<bool LAST>
__global__ __launch_bounds__(256) void ff2qkv_kernel(
    const u16* __restrict__ ff, const u16* __restrict__ W2T, const float* __restrict__ b2,
    const float* __restrict__ lng, const float* __restrict__ lnb,
    const u16* __restrict__ WqkvT,
    const float* __restrict__ bq, const float* __restrict__ bk, const float* __restrict__ bv,
    float* __restrict__ x, u16* __restrict__ hout, u16* __restrict__ qkv)
{
    __shared__ u16 As[2][16*64];
    __shared__ u16 Bs[2][256*64];
    __shared__ u16 hS[16][264];
    __shared__ float sred[4][16], qred[4][16];

    int tid = threadIdx.x;
    int lane = tid & 63, w = tid >> 6;
    int lr = lane & 15, lg = lane >> 4;
    int bid = xcd_swizzle(blockIdx.x, 256);
    int row0 = bid * 16;

    auto stageB = [&](int buf, const u16* BT, int K, int k0) {
        #pragma unroll
        for (int i = 0; i < 8; i++) {
            int o16 = tid + i * 256;
            int r = o16 >> 3;
            int sw = ((o16 & 7) << 4) ^ ((r & 7) << 4);
            GLOAD16(BT + (size_t)r * K + k0 + (sw >> 1), &Bs[buf][o16 * 8]);
        }
    };
    auto stageA = [&](int buf, int k0) {
        if (tid < 128) {
            int r = tid >> 3;
            int sw = ((tid & 7) << 4) ^ ((r & 7) << 4);
            GLOAD16(ff + (size_t)(row0 + r) * DF_ + k0 + (sw >> 1), &As[buf][tid * 8]);
        }
    };
    auto prefetch = [&](int u) {
        if (u < 16) { stageA(u & 1, u * 64); stageB(u & 1, W2T, 1024, u * 64); }
        else if (!LAST && u < 28) {
            int v = u - 16;
            stageB(u & 1, WqkvT + (size_t)(v >> 2) * 65536, 256, (v & 3) * 64);
        }
    };
    auto afA = [&](int buf, int ks) -> bf16x8 {
        return *(const bf16x8*)(&As[buf][lr * 64 + (((ks * 64 + lg * 16) ^ ((lr & 7) << 4)) >> 1)]);
    };
    auto afH = [&](int t, int ks) -> bf16x8 {
        return *(const bf16x8*)(&hS[lr][(t * 128 + ks * 64 + lg * 16) >> 1]);
    };
    auto bfr = [&](int buf, int ni, int ks) -> bf16x8 {
        int rr = w * 64 + ni * 16 + lr;
        return *(const bf16x8*)(&Bs[buf][rr * 64 + (((ks * 64 + lg * 16) ^ ((rr & 7) << 4)) >> 1)]);
    };

    prefetch(0);
    f32x4 acc[4] = {};
    for (int u = 0; u < 16; u++) {
        __syncthreads();
        prefetch(u + 1);
        #pragma unroll
        for (int ks = 0; ks < 2; ks++) {
            bf16x8 a = afA(u & 1, ks);
            __builtin_amdgcn_s_setprio(1);
            #pragma unroll
            for (int ni = 0; ni < 4; ni++)
                acc[ni] = __builtin_amdgcn_mfma_f32_16x16x32_bf16(a, bfr(u & 1, ni, ks), acc[ni], 0, 0, 0);
            __builtin_amdgcn_s_setprio(0);
        }
    }

    // epilogue: +b2 + residual -> x, LN(next) -> hS (and hout if LAST)
    {
        float vals[4][4];
        float rs[4] = {0,0,0,0}, rq[4] = {0,0,0,0};
        #pragma unroll
        for (int ni = 0; ni < 4; ni++)
            #pragma unroll
            for (int j = 0; j < 4; j++) {
                int row = row0 + lg * 4 + j;
                int col = w * 64 + ni * 16 + lr;
                float v = acc[ni][j] + b2[col] + x[(size_t)row * D_ + col];
                x[(size_t)row * D_ + col] = v;
                vals[ni][j] = v;
                rs[j] += v; rq[j] += v * v;
            }
        #pragma unroll
        for (int j = 0; j < 4; j++)
            #pragma unroll
            for (int o = 1; o <= 8; o <<= 1) { rs[j] += __shfl_xor(rs[j], o); rq[j] += __shfl_xor(rq[j], o); }
        if (lr == 0)
            #pragma unroll
            for (int j = 0; j < 4; j++) { sred[w][lg*4 + j] = rs[j]; qred[w][lg*4 + j] = rq[j]; }
        __syncthreads();
        #pragma unroll
        for (int j = 0; j < 4; j++) {
            int r = lg * 4 + j;
            float mu = (sred[0][r] + sred[1][r] + sred[2][r] + sred[3][r]) * (1.0f / D_);
            float var = (qred[0][r] + qred[1][r] + qred[2][r] + qred[3][r]) * (1.0f / D_) - mu * mu;
            float ri = rsqrtf(var + 1e-5f);
            #pragma unroll
            for (int ni = 0; ni < 4; ni++) {
                int col = w * 64 + ni * 16 + lr;
                float hv = (vals[ni][j] - mu) * ri * lng[col] + lnb[col];
                if (LAST) hout[(size_t)(row0 + r) * D_ + col] = f2bf(hv);
                else      hS[r][col] = f2bf(hv);
            }
        }
    }

    if constexpr (!LAST) {
        f32x4 accT[4] = {};
        for (int v = 0; v < 12; v++) {
            __syncthreads();
            prefetch(16 + v + 1);
            int t = v & 3;
            #pragma unroll
            for (int ks = 0; ks < 2; ks++) {
                bf16x8 a = afH(t, ks);
                __builtin_amdgcn_s_setprio(1);
                #pragma unroll
                for (int ni = 0; ni < 4; ni++)
                    accT[ni] = __builtin_amdgcn_mfma_f32_16x16x32_bf16(a, bfr(v & 1, ni, ks), accT[ni], 0, 0, 0);
                __builtin_amdgcn_s_setprio(0);
            }
            if (t == 3) {
                int sel = v >> 2;
                const float* bp = sel == 0 ? bq : sel == 1 ? bk : bv;
                #pragma unroll
                for (int ni = 0; ni < 4; ni++) {
                    #pragma unroll
                    for (int j = 0; j < 4; j++) {
                        int row = row0 + lg * 4 + j;
                        int cc = w * 64 + ni * 16 + lr;
                        float val = accT[ni][j] + bp[cc];
                        int bb = row >> 11, tt = row & (T_ - 1);
                        int hh = cc >> 6, dh = cc & 63;
                        qkv[(size_t)sel * NTOK * D_ +
                            ((((size_t)bb * H_ + hh) * T_) + tt) * DH_ + dh] = f2bf(val);
                    }
                    accT[ni] = (f32x4){0.f, 0.f, 0.f, 0.f};
                }
            }
        }
    }
}

// ================= MFMA causal flash attention =================
__global__ __launch_bounds__(256) void attn_kernel(
    const u16* __restrict__ q, const u16* __restrict__ k,
    const u16* __restrict__ v, u16* __restrict__ y)
{
    int qb = blockIdx.x;
    int bh = blockIdx.y;
    int bidx = bh >> 2, h = bh & 3;
    const u16* qp = q + (size_t)bh * T_ * DH_;
    const u16* kp = k + (size_t)bh * T_ * DH_;
    const u16* vp = v + (size_t)bh * T_ * DH_;

    __shared__ u16 Qs[64*64];
    __shared__ u16 Ks[2][64*64];
    __shared__ u16 VT[2][64*72];
    __shared__ u16 Ps[4][16*72];

    int tid = threadIdx.x;
    int lane = tid & 63, w = tid >> 6;
    int lr = lane & 15, lg = lane >> 4;
    int vkey = tid & 63;
    int vdh0 = (tid >> 6) * 8;

    #pragma unroll
    for (int i = 0; i < 2; i++) {
        int o16 = tid + i * 256;
        int r = o16 >> 3;
        int sw = ((o16 & 7) << 4) ^ ((r & 7) << 4);
        GLOAD16(qp + (size_t)(qb * 64 + r) * DH_ + (sw >> 1), &Qs[o16 * 8]);
        GLOAD16(kp + (size_t)r * DH_ + (sw >> 1), &Ks[0][o16 * 8]);
    }
    bf16x8 vva = *(const bf16x8*)(vp + (size_t)vkey * DH_ + vdh0);
    bf16x8 vvb = *(const bf16x8*)(vp + (size_t)vkey * DH_ + vdh0 + 32);
    __syncthreads();
    #pragma unroll
    for (int e = 0; e < 8; e++) {
        VT[0][(vdh0 + e) * 72 + vkey] = (u16)vva[e];
        VT[0][(vdh0 + 32 + e) * 72 + vkey] = (u16)vvb[e];
    }
    bf16x8 qa[2];
    #pragma unroll
    for (int ks = 0; ks < 2; ks++) {
        int rr = w * 16 + lr;
        qa[ks] = *(const bf16x8*)(Qs + rr * 64 + (((ks * 64 + lg * 16) ^ ((rr & 7) << 4)) >> 1));
    }
    __syncthreads();

    float m[4], lden[4];
    f32x4 o[4] = {};
    #pragma unroll
    for (int j = 0; j < 4; j++) { m[j] = -1e30f; lden[j] = 0.0f; }

    for (int kc = 0; kc <= qb; kc++) {
        int cur = kc & 1, nxt = cur ^ 1;
        bf16x8 nva, nvb;
        if (kc < qb) {
            #pragma unroll
            for (int i = 0; i < 2; i++) {
                int o16 = tid + i * 256;
                int r = o16 >> 3;
                int sw = ((o16 & 7) << 4) ^ ((r & 7) << 4);
                GLOAD16(kp + (size_t)((kc + 1) * 64 + r) * DH_ + (sw >> 1), &Ks[nxt][o16 * 8]);
            }
            nva = *(const bf16x8*)(vp + (size_t)((kc + 1) * 64 + vkey) * DH_ + vdh0);
            nvb = *(const bf16x8*)(vp + (size_t)((kc + 1) * 64 + vkey) * DH_ + vdh0 + 32);
        }

        f32x4 sc[4];
        #pragma unroll
        for (int ct = 0; ct < 4; ct++) {
            f32x4 s = {};
            __builtin_amdgcn_s_setprio(1);
            #pragma unroll
            for (int ks = 0; ks < 2; ks++) {
                int rr = ct * 16 + lr;
                bf16x8 kb = *(const bf16x8*)(&Ks[cur][rr * 64 + (((ks * 64 + lg * 16) ^ ((rr & 7) << 4)) >> 1)]);
                s = __builtin_amdgcn_mfma_f32_16x16x32_bf16(qa[ks], kb, s, 0, 0, 0);
            }
            __builtin_amdgcn_s_setprio(0);
            sc[ct] = s;
        }
        float mloc[4];
        #pragma unroll
        for (int j = 0; j < 4; j++) mloc[j] = -1e30f;
        #pragma unroll
        for (int ct = 0; ct < 4; ct++)
            #pragma unroll
            for (int j = 0; j < 4; j++) {
                float s = sc[ct][j] * 0.125f;
                if (kc == qb && (ct * 16 + lr) > (w * 16 + lg * 4 + j)) s = -1e30f;
                sc[ct][j] = s;
                mloc[j] = fmaxf(mloc[j], s);
            }
        #pragma unroll
        for (int j = 0; j < 4; j++) {
            mloc[j] = fmaxf(mloc[j], __shfl_xor(mloc[j], 1));
            mloc[j] = fmaxf(mloc[j], __shfl_xor(mloc[j], 2));
            mloc[j] = fmaxf(mloc[j], __shfl_xor(mloc[j], 4));
            mloc[j] = fmaxf(mloc[j], __shfl_xor(mloc[j], 8));
        }
        float f[4], rs[4];
        #pragma unroll
        for (int j = 0; j < 4; j++) {
            float nm = fmaxf(m[j], mloc[j]);
            f[j] = __expf(m[j] - nm);
            m[j] = nm;
            rs[j] = 0.0f;
        }
        #pragma unroll
        for (int ct = 0; ct < 4; ct++)
            #pragma unroll
            for (int j = 0; j < 4; j++) {
                float p = __expf(sc[ct][j] - m[j]);
                rs[j] += p;
                Ps[w][(lg * 4 + j) * 72 + ct * 16 + lr] = f2bf(p);
            }
        #pragma unroll
        for (int j = 0; j < 4; j++) {
            rs[j] += __shfl_xor(rs[j], 1);
            rs[j] += __shfl_xor(rs[j], 2);
            rs[j] += __shfl_xor(rs[j], 4);
            rs[j] += __shfl_xor(rs[j], 8);
            lden[j] = lden[j] * f[j] + rs[j];
        }
        #pragma unroll
        for (int dt = 0; dt < 4; dt++)
            #pragma unroll
            for (int j = 0; j < 4; j++)
                o[dt][j] *= f[j];
        #pragma unroll
        for (int ks = 0; ks < 2; ks++) {
            bf16x8 pa = *(const bf16x8*)(&Ps[w][lr * 72 + ks * 32 + lg * 8]);
            __builtin_amdgcn_s_setprio(1);
            #pragma unroll
            for (int dt = 0; dt < 4; dt++) {
                bf16x8 vb = *(const bf16x8*)(&VT[cur][(dt * 16 + lr) * 72 + ks * 32 + lg * 8]);
                o[dt] = __builtin_amdgcn_mfma_f32_16x16x32_bf16(pa, vb, o[dt], 0, 0, 0);
            }
            __builtin_amdgcn_s_setprio(0);
        }
        if (kc < qb) {
            #pragma unroll
            for (int e = 0; e < 8; e++) {
                VT[nxt][(vdh0 + e) * 72 + vkey] = (u16)nva[e];
                VT[nxt][(vdh0 + 32 + e) * 72 + vkey] = (u16)nvb[e];
            }
        }
        __syncthreads();
    }

    #pragma unroll
    for (int j = 0; j < 4; j++) {
        float inv = 1.0f / lden[j];
        int q_g = qb * 64 + w * 16 + lg * 4 + j;
        size_t base = ((size_t)(bidx * T_ + q_g)) * D_ + h * DH_;
        #pragma unroll
        for (int dt = 0; dt < 4; dt++)
            y[base + dt * 16 + lr] = f2bf(o[dt][j] * inv);
    }
}

// ================= head GEMM (128x128 MFMA, double-buffered, nt stores) ============
__global__ __launch_bounds__(256) void head_gemm(
    const u16* __restrict__ A, const u16* __restrict__ BT,
    const float* __restrict__ bias, float* __restrict__ C,
    int M, int N, int K)
{
    __shared__ u16 As[2][128*64];
    __shared__ u16 Bs[2][128*64];
    int tid = threadIdx.x;
    int lane = tid & 63, w = tid >> 6;
    int lr = lane & 15, lg = lane >> 4;
    int wm = w >> 1, wn = w & 1;

    int gx = gridDim.x;
    int nwg = gx * gridDim.y;
    int orig = blockIdx.y * gx + blockIdx.x;
    int bid = xcd_swizzle(orig, nwg);
    int row0 = (bid / gx) * 128, col0 = (bid % gx) * 128;

    f32x4 acc[4][4] = {};

    auto stage = [&](int buf, int k0) {
        #pragma unroll
        for (int i = 0; i < 4; i++) {
            int o16 = tid + i * 256;
            int r = o16 >> 3;
            int sw = ((o16 & 7) << 4) ^ ((r & 7) << 4);
            GLOAD16(A + (size_t)(row0 + r) * K + k0 + (sw >> 1), &As[buf][o16 * 8]);
            GLOAD16(BT + (size_t)(col0 + r) * K + k0 + (sw >> 1), &Bs[buf][o16 * 8]);
        }
    };

    stage(0, 0);
    int nk = K >> 6;
    for (int t = 0; t < nk; t++) {
        int cur = t & 1;
        __syncthreads();
        if (t + 1 < nk) stage(cur ^ 1, (t + 1) << 6);
        #pragma unroll
        for (int ks = 0; ks < 2; ks++) {
            bf16x8 af[4], bfr[4];
            #pragma unroll
            for (int mi = 0; mi < 4; mi++) {
                int rr = wm * 64 + mi * 16 + lr;
                af[mi] = *(const bf16x8*)(&As[cur][rr * 64 + (((ks * 64 + lg * 16) ^ ((rr & 7) << 4)) >> 1)]);
            }
            #pragma unroll
            for (int ni = 0; ni < 4; ni++) {
                int rr = wn * 64 + ni * 16 + lr;
                bfr[ni] = *(const bf16x8*)(&Bs[cur][rr * 64 + (((ks * 64 + lg * 16) ^ ((rr & 7) << 4)) >> 1)]);
            }
            __builtin_amdgcn_s_setprio(1);
            #pragma unroll
            for (int mi = 0; mi < 4; mi++)
                #pragma unroll
                for (int ni = 0; ni < 4; ni++)
                    acc[mi][ni] = __builtin_amdgcn_mfma_f32_16x16x32_bf16(af[mi], bfr[ni], acc[mi][ni], 0, 0, 0);
            __builtin_amdgcn_s_setprio(0);
        }
    }

    #pragma unroll
    for (int mi = 0; mi < 4; mi++)
        #pragma unroll
        for (int ni = 0; ni < 4; ni++)
            #pragma unroll
            for (int j = 0; j < 4; j++) {
                int row = row0 + wm * 64 + mi * 16 + lg * 4 + j;
                int col = col0 + wn * 64 + ni * 16 + lr;
                __builtin_nontemporal_store(acc[mi][ni][j] + bias[col], &C[(size_t)row * N + col]);
            }
}

// ================= host launch =================
extern "C" void kernel_launch(void* const* d_in, const int* in_sizes, int n_in,
                              void* d_out, int out_size, void* d_ws, size_t ws_size,
                              hipStream_t stream)
{
    const int*   idx  = (const int*)d_in[0];
    const float* tok  = (const float*)d_in[1];
    const float* pos  = (const float*)d_in[2];
    const float* Wq   = (const float*)d_in[3];
    const float* bq   = (const float*)d_in[4];
    const float* Wk   = (const float*)d_in[5];
    const float* bk   = (const float*)d_in[6];
    const float* Wv   = (const float*)d_in[7];
    const float* bv   = (const float*)d_in[8];
    const float* Wo   = (const float*)d_in[9];
    const float* bo   = (const float*)d_in[10];
    const float* ln1g = (const float*)d_in[11];
    const float* ln1b = (const float*)d_in[12];
    const float* W1   = (const float*)d_in[13];
    const float* b1   = (const float*)d_in[14];
    const float* W2   = (const float*)d_in[15];
    const float* b2   = (const float*)d_in[16];
    const float* ln2g = (const float*)d_in[17];
    const float* ln2b = (const float*)d_in[18];
    const float* lnfg = (const float*)d_in[19];
    const float* lnfb = (const float*)d_in[20];
    const float* hW   = (const float*)d_in[21];
    const float* hb   = (const float*)d_in[22];

    char* p = (char*)d_ws;
    float* x     = (float*)p;           p += (size_t)NTOK * D_ * 4;
    u16* hbuf    = (u16*)p;             p += (size_t)NTOK * D_ * 2;
    u16* qkvbuf  = (u16*)p;             p += (size_t)3 * NTOK * D_ * 2;
    u16* ybuf    = (u16*)p;             p += (size_t)NTOK * D_ * 2;
    u16* ff      = (u16*)p;             p += (size_t)NTOK * DF_ * 2;
    u16* WqkvT   = (u16*)p;             p += (size_t)L_ * 768 * D_ * 2;
    u16* WoT     = (u16*)p;             p += (size_t)L_ * D_ * D_ * 2;
    u16* W1T     = (u16*)p;             p += (size_t)L_ * D_ * DF_ * 2;
    u16* W2T     = (u16*)p;             p += (size_t)L_ * DF_ * D_ * 2;
    u16* hWT     = (u16*)p;             p += (size_t)V_ * D_ * 2;

    u16* qbuf = qkvbuf;
    u16* kbuf = qkvbuf + (size_t)NTOK * D_;
    u16* vbuf = qkvbuf + (size_t)2 * NTOK * D_;

    prep_kernel<<<11072, 256, 0, stream>>>(Wq, Wk, Wv, Wo, W1, W2, hW,
                                           WqkvT, WoT, W1T, W2T, hWT);

    embed_qkv_kernel<<<256, 256, 0, stream>>>(idx, tok, pos, ln1g, ln1b,
                                              WqkvT, bq, bk, bv, x, qkvbuf);

    dim3 gAttn(T_ / 64, B_ * H_);        // (32, 8)
    dim3 gFF1(DF_ / 64, NTOK / 64);      // (16, 64)
    for (int l = 0; l < L_; l++) {
        attn_kernel<<<gAttn, 256, 0, stream>>>(qbuf, kbuf, vbuf, ybuf);
        wo_ln_kernel<<<256, 256, 0, stream>>>(ybuf, WoT + (size_t)l * 65536, bo + l * D_,
                                              ln2g + l * D_, ln2b + l * D_, x, hbuf);
        ff1_kernel<<<gFF1, 256, 0, stream>>>(hbuf, W1T + (size_t)l * 262144, b1 + l * DF_, ff);
        if (l < L_ - 1) {
            ff2qkv_kernel<false><<<256, 256, 0, stream>>>(
                ff, W2T + (size_t)l * 262144, b2 + l * D_,
                ln1g + (l + 1) * D_, ln1b + (l + 1) * D_,
                WqkvT + (size_t)(l + 1) * 196608,
                bq + (l + 1) * D_, bk + (l + 1) * D_, bv + (l + 1) * D_,
                x, nullptr, qkvbuf);
        } else {
            ff2qkv_kernel<true><<<256, 256, 0, stream>>>(
                ff, W2T + (size_t)l * 262144, b2 + l * D_,
                lnfg, lnfb,
                nullptr, nullptr, nullptr, nullptr,
                x, hbuf, nullptr);
        }
    }

    dim3 gHead(V_ / 128, NTOK / 128);    // (250, 32)
    head_gemm<<<gHead, 256, 0, stream>>>(hbuf, hWT, hb, (float*)d_out, NTOK, V_, D_);
}